// Round 7
// baseline (73.611 us; speedup 1.0000x reference)
//
#include <hip/hip_runtime.h>
#include <hip/hip_bf16.h>
#include <math.h>

#define F 64
#define TILE 16

typedef __attribute__((ext_vector_type(8))) short bf16x8;
typedef __attribute__((ext_vector_type(4))) float f32x4;

union BF8 { bf16x8 v; unsigned u[4]; };

#define LOG2E 1.4426950408889634f

__device__ __forceinline__ float fast_exp(float x) {          // e^x
    return __builtin_amdgcn_exp2f(x * LOG2E);
}
__device__ __forceinline__ float fast_sigmoid(float x) {
    return __builtin_amdgcn_rcpf(1.0f + fast_exp(-x));
}
__device__ __forceinline__ float fast_silu(float x) {
    return x * __builtin_amdgcn_rcpf(1.0f + fast_exp(-x));
}
// pack two floats to bf16 pair (round-half-up; inputs finite)
__device__ __forceinline__ unsigned pk2(float a, float b) {
    const unsigned ua = __builtin_bit_cast(unsigned, a);
    const unsigned ub = __builtin_bit_cast(unsigned, b);
    return ((ua + 0x8000u) >> 16) | ((ub + 0x8000u) & 0xFFFF0000u);
}
__device__ __forceinline__ short f2bf(float x) {
    __hip_bfloat16 h = __float2bfloat16(x);
    return __builtin_bit_cast(short, h);
}

// ---------------------------------------------------------------------------
// Kernel 1: per-node half layer-1 outputs (bias folded):
//   y[i][f] = 0.5*(x[i]@lW1)[f] + 0.5*lb1[f];  z likewise for gate branch.
// ---------------------------------------------------------------------------
__global__ void precompute_yz(const float* __restrict__ x,
                              const float* __restrict__ lW1, const float* __restrict__ lb1,
                              const float* __restrict__ gW1, const float* __restrict__ gb1,
                              float* __restrict__ y, float* __restrict__ z) {
    __shared__ float xs[F];
    const int i = blockIdx.x;
    const int f = threadIdx.x;
    xs[f] = x[i * F + f];
    __syncthreads();
    float accY = 0.f, accZ = 0.f;
#pragma unroll
    for (int k = 0; k < F; ++k) {
        const float xv = xs[k];
        accY += xv * lW1[k * F + f];
        accZ += xv * gW1[k * F + f];
    }
    y[i * F + f] = 0.5f * accY + 0.5f * lb1[f];
    z[i * F + f] = 0.5f * accZ + 0.5f * gb1[f];
}

// ---------------------------------------------------------------------------
// Kernel 2: pre-swizzle layer-2 weights into per-lane MFMA fragments
// (A-fragment of W^T == B-fragment of W in the m89 layout).
//   wf[ b*8192 + kt*4096 + ft*1024 + s*512 + lane*8 + e ]
//   = W_b[k][f],  k = kt*32 + (lane>>4)*8 + e,  f = ft*16 + (lane&15)
// (s=1 lo-residual entries still written but no longer read.)
// ---------------------------------------------------------------------------
__global__ void prep_wfrags(const float* __restrict__ lW2,
                            const float* __restrict__ gW2,
                            short* __restrict__ wf) {
    const int idx = blockIdx.x * 256 + threadIdx.x;   // 0..16383
    const int e    = idx & 7;
    const int lane = (idx >> 3) & 63;
    const int s    = (idx >> 9) & 1;
    const int ft   = (idx >> 10) & 3;
    const int kt   = (idx >> 12) & 1;
    const int b    = (idx >> 13) & 1;
    const int k = kt * 32 + ((lane >> 4) << 3) + e;
    const int f = ft * 16 + (lane & 15);
    const float* W = b ? gW2 : lW2;
    const float w = W[k * F + f];
    const __hip_bfloat16 hi = __float2bfloat16(w);
    const float v = (s == 0) ? w : (w - __bfloat162float(hi));
    wf[idx] = f2bf(v);
}

// ---------------------------------------------------------------------------
// One branch: out2^T = W2^T @ act1^T via MFMA, fused layer 3.
// pt-blocked (2 pairs at a time) to keep the live register set ~56 VGPR:
//   bfrag 16 + W 8 + acc 4 + part 4 + temps.
// ---------------------------------------------------------------------------
__device__ __forceinline__ void run_branch(
    const float (*si)[F + 4], const float (*sj)[F + 4],
    const short* __restrict__ wfb,       // branch base (8192 shorts)
    const float* sB2, const float* sW3,
    int w, int g, int c, float (&part)[4]) {

    const int l = g * 16 + c;
    part[0] = part[1] = part[2] = part[3] = 0.f;

#pragma unroll
    for (int ptb = 0; ptb < 2; ++ptb) {
        // ---- B-fragments for pairs (4w + 2ptb + p, c), p=0,1 ----
        BF8 bf[2][2];
#pragma unroll
        for (int kt = 0; kt < 2; ++kt) {
            const float* pj = &sj[c][kt * 32 + 8 * g];
            const float4 j0v = *(const float4*)(pj);
            const float4 j1v = *(const float4*)(pj + 4);
#pragma unroll
            for (int p = 0; p < 2; ++p) {
                const float* pi = &si[4 * w + 2 * ptb + p][kt * 32 + 8 * g]; // wave-uniform
                const float4 i0v = *(const float4*)(pi);
                const float4 i1v = *(const float4*)(pi + 4);
                bf[kt][p].u[0] = pk2(fast_silu(i0v.x + j0v.x), fast_silu(i0v.y + j0v.y));
                bf[kt][p].u[1] = pk2(fast_silu(i0v.z + j0v.z), fast_silu(i0v.w + j0v.w));
                bf[kt][p].u[2] = pk2(fast_silu(i1v.x + j1v.x), fast_silu(i1v.y + j1v.y));
                bf[kt][p].u[3] = pk2(fast_silu(i1v.z + j1v.z), fast_silu(i1v.w + j1v.w));
            }
        }

#pragma unroll
        for (int ft = 0; ft < 4; ++ft) {
            const short* base = wfb + ft * 1024 + l * 8;
            const bf16x8 wh0 = *(const bf16x8*)(base);           // kt=0
            const bf16x8 wh1 = *(const bf16x8*)(base + 4096);    // kt=1
            const float4 b2v = *(const float4*)&sB2[ft * 16 + 4 * g];
            const float4 w3v = *(const float4*)&sW3[ft * 16 + 4 * g];
#pragma unroll
            for (int p = 0; p < 2; ++p) {
                f32x4 acc = (f32x4){b2v.x, b2v.y, b2v.z, b2v.w};  // bias preloaded
                acc = __builtin_amdgcn_mfma_f32_16x16x32_bf16(wh0, bf[0][p].v, acc, 0, 0, 0);
                acc = __builtin_amdgcn_mfma_f32_16x16x32_bf16(wh1, bf[1][p].v, acc, 0, 0, 0);
                part[2 * ptb + p] += fast_silu(acc[0]) * w3v.x
                                   + fast_silu(acc[1]) * w3v.y
                                   + fast_silu(acc[2]) * w3v.z
                                   + fast_silu(acc[3]) * w3v.w;
            }
        }
    }
}

// ---------------------------------------------------------------------------
// Kernel 3: 16x16 pair tile per block (upper triangle), transposed MFMA.
// (256,4): target the 64-VGPR bin -> ~4 waves/SIMD (unified VGPR+AGPR file
// makes effective footprint ~2x VGPR_Count; R3-R6 occupancy series).
// ---------------------------------------------------------------------------
__global__ __launch_bounds__(256, 4) void pair_mlp_mfma(
    const float* __restrict__ y, const float* __restrict__ z,
    const short* __restrict__ wf,
    const float* __restrict__ lb2, const float* __restrict__ lW3, const float* __restrict__ lb3,
    const float* __restrict__ gb2, const float* __restrict__ gW3, const float* __restrict__ gb3,
    float* __restrict__ out, int N) {

    __shared__ __align__(16) float smem[4608];   // 18432 B
    float (*ysi)[F + 4] = (float (*)[F + 4])(smem + 0);      // 16x68
    float (*zsi)[F + 4] = (float (*)[F + 4])(smem + 1088);
    float (*ysj)[F + 4] = (float (*)[F + 4])(smem + 2176);
    float (*zsj)[F + 4] = (float (*)[F + 4])(smem + 3264);
    float* sB2l = smem + 4352;
    float* sW3l = smem + 4416;
    float* sB2g = smem + 4480;
    float* sW3g = smem + 4544;
    // epilogue aliases (used only after a __syncthreads once y/z reads done)
    float (*valD)[TILE + 1] = (float (*)[TILE + 1])(smem + 0);
    float (*valT)[TILE + 1] = (float (*)[TILE + 1])(smem + 1088);

    const int bid = blockIdx.x;
    int tj = (int)((sqrtf(8.0f * (float)bid + 1.0f) - 1.0f) * 0.5f);
    while ((tj + 1) * (tj + 2) / 2 <= bid) ++tj;
    while (tj * (tj + 1) / 2 > bid) --tj;
    const int ti = bid - tj * (tj + 1) / 2;   // ti <= tj
    const int i0 = ti * TILE, j0 = tj * TILE;

    const int t = threadIdx.x;

    // ---- stage y/z row tiles ----
    {
        const int r = t >> 4;
        const int e4 = t & 15;
        const float4* yv = (const float4*)y;
        const float4* zv = (const float4*)z;
        *(float4*)&ysi[r][e4 * 4] = yv[(size_t)(i0 + r) * (F / 4) + e4];
        *(float4*)&zsi[r][e4 * 4] = zv[(size_t)(i0 + r) * (F / 4) + e4];
        *(float4*)&ysj[r][e4 * 4] = yv[(size_t)(j0 + r) * (F / 4) + e4];
        *(float4*)&zsj[r][e4 * 4] = zv[(size_t)(j0 + r) * (F / 4) + e4];
    }
    if (t < F) {
        sB2l[t] = lb2[t];
        sW3l[t] = lW3[t];
        sB2g[t] = gb2[t];
        sW3g[t] = gW3[t];
    }
    __syncthreads();

    const int w = t >> 6;     // wave 0..3
    const int l = t & 63;
    const int g = l >> 4;
    const int c = l & 15;

    float partL[4], partG[4];
    run_branch(ysi, ysj, wf,        sB2l, sW3l, w, g, c, partL);
    run_branch(zsi, zsj, wf + 8192, sB2g, sW3g, w, g, c, partG);

    // ---- reduce across the 4 lane groups (features) ----
#pragma unroll
    for (int pt = 0; pt < 4; ++pt) {
        partL[pt] += __shfl_xor(partL[pt], 16, 64);
        partL[pt] += __shfl_xor(partL[pt], 32, 64);
        partG[pt] += __shfl_xor(partG[pt], 16, 64);
        partG[pt] += __shfl_xor(partG[pt], 32, 64);
    }

    const float b3l = lb3[0];
    const float b3g = gb3[0];

    __syncthreads();   // all y/z LDS reads complete before aliasing region

    if (g == 0) {
#pragma unroll
        for (int pt = 0; pt < 4; ++pt) {
            const float m3 = partL[pt] + b3l;
            const float g3 = partG[pt] + b3g;
            const float v = m3 * fast_sigmoid(g3);
            valD[4 * w + pt][c] = v;
            valT[c][4 * w + pt] = v;
        }
    }
    __syncthreads();

    // ---- single-phase coalesced stores of both mirrored tiles ----
    {
        const int r = t >> 4;
        const int cc = t & 15;
        out[(size_t)(i0 + r) * N + (j0 + cc)] = valD[r][cc];
        out[(size_t)(j0 + r) * N + (i0 + cc)] = valT[r][cc];
    }
}

extern "C" void kernel_launch(void* const* d_in, const int* in_sizes, int n_in,
                              void* d_out, int out_size, void* d_ws, size_t ws_size,
                              hipStream_t stream) {
    const float* node_feat = (const float*)d_in[0];
    const float* lW1 = (const float*)d_in[1];
    const float* lb1 = (const float*)d_in[2];
    const float* lW2 = (const float*)d_in[3];
    const float* lb2 = (const float*)d_in[4];
    const float* lW3 = (const float*)d_in[5];
    const float* lb3 = (const float*)d_in[6];
    const float* gW1 = (const float*)d_in[7];
    const float* gb1 = (const float*)d_in[8];
    const float* gW2 = (const float*)d_in[9];
    const float* gb2 = (const float*)d_in[10];
    const float* gW3 = (const float*)d_in[11];
    const float* gb3 = (const float*)d_in[12];

    const int N = in_sizes[0] / F;   // 1024

    float* y = (float*)d_ws;                     // N*F floats
    float* z = y + (size_t)N * F;                // N*F floats
    short* wfrag = (short*)(z + (size_t)N * F);  // 16384 shorts (32 KB)

    precompute_yz<<<N, F, 0, stream>>>(node_feat, lW1, lb1, gW1, gb1, y, z);
    prep_wfrags<<<64, 256, 0, stream>>>(lW2, gW2, wfrag);

    const int nT = N / TILE;                   // 64
    const int nBlocks = nT * (nT + 1) / 2;     // 2080
    pair_mlp_mfma<<<nBlocks, 256, 0, stream>>>(y, z, wfrag,
                                               lb2, lW3, lb3,
                                               gb2, gW3, gb3,
                                               (float*)d_out, N);
}

// Round 8
// 57.509 us; speedup vs baseline: 1.2800x; 1.2800x over previous
//
#include <hip/hip_runtime.h>
#include <hip/hip_bf16.h>
#include <math.h>

#define F 64
#define TILE 16

typedef __attribute__((ext_vector_type(8))) short bf16x8;
typedef __attribute__((ext_vector_type(4))) float f32x4;

union BF8 { bf16x8 v; unsigned u[4]; };

#define LOG2E 1.4426950408889634f

__device__ __forceinline__ float fast_exp(float x) {          // e^x
    return __builtin_amdgcn_exp2f(x * LOG2E);
}
__device__ __forceinline__ float fast_sigmoid(float x) {
    return __builtin_amdgcn_rcpf(1.0f + fast_exp(-x));
}
__device__ __forceinline__ float fast_silu(float x) {
    return x * __builtin_amdgcn_rcpf(1.0f + fast_exp(-x));
}
// pack two floats to bf16 pair (round-half-up; inputs finite)
__device__ __forceinline__ unsigned pk2(float a, float b) {
    const unsigned ua = __builtin_bit_cast(unsigned, a);
    const unsigned ub = __builtin_bit_cast(unsigned, b);
    return ((ua + 0x8000u) >> 16) | ((ub + 0x8000u) & 0xFFFF0000u);
}
__device__ __forceinline__ short f2bf(float x) {
    __hip_bfloat16 h = __float2bfloat16(x);
    return __builtin_bit_cast(short, h);
}

// ---------------------------------------------------------------------------
// Kernel 1: per-node half layer-1 outputs (bias folded):
//   y[i][f] = 0.5*(x[i]@lW1)[f] + 0.5*lb1[f];  z likewise for gate branch.
// ---------------------------------------------------------------------------
__global__ void precompute_yz(const float* __restrict__ x,
                              const float* __restrict__ lW1, const float* __restrict__ lb1,
                              const float* __restrict__ gW1, const float* __restrict__ gb1,
                              float* __restrict__ y, float* __restrict__ z) {
    __shared__ float xs[F];
    const int i = blockIdx.x;
    const int f = threadIdx.x;
    xs[f] = x[i * F + f];
    __syncthreads();
    float accY = 0.f, accZ = 0.f;
#pragma unroll
    for (int k = 0; k < F; ++k) {
        const float xv = xs[k];
        accY += xv * lW1[k * F + f];
        accZ += xv * gW1[k * F + f];
    }
    y[i * F + f] = 0.5f * accY + 0.5f * lb1[f];
    z[i * F + f] = 0.5f * accZ + 0.5f * gb1[f];
}

// ---------------------------------------------------------------------------
// Kernel 2: pre-swizzle layer-2 weights into per-lane MFMA fragments
// (A-fragment of W^T == B-fragment of W in the m89 layout), hi bf16 only
// (R7: hi-only weights measured zero absmax impact).
//   wf[ b*4096 + kt*2048 + ft*512 + lane*8 + e ]
//   = bf16(W_b[k][f]),  k = kt*32 + (lane>>4)*8 + e,  f = ft*16 + (lane&15)
// ---------------------------------------------------------------------------
__global__ void prep_wfrags(const float* __restrict__ lW2,
                            const float* __restrict__ gW2,
                            short* __restrict__ wf) {
    const int idx = blockIdx.x * 256 + threadIdx.x;   // 0..8191
    const int e    = idx & 7;
    const int lane = (idx >> 3) & 63;
    const int ft   = (idx >> 9) & 3;
    const int kt   = (idx >> 11) & 1;
    const int b    = (idx >> 12) & 1;
    const int k = kt * 32 + ((lane >> 4) << 3) + e;
    const int f = ft * 16 + (lane & 15);
    const float* W = b ? gW2 : lW2;
    wf[idx] = f2bf(W[k * F + f]);
}

// ---------------------------------------------------------------------------
// Both branches fused: out2^T = W2^T @ act1^T via MFMA, fused layer 3.
// pt-blocked (2 pairs at a time); L and G interleaved for ILP (4 independent
// MFMA chains + 2x independent silu groups per scheduling region).
// ---------------------------------------------------------------------------
__device__ __forceinline__ void run_both(
    const float (*ysi)[F + 4], const float (*ysj)[F + 4],
    const float (*zsi)[F + 4], const float (*zsj)[F + 4],
    const short* __restrict__ wfL, const short* __restrict__ wfG,
    const float* sB2l, const float* sW3l,
    const float* sB2g, const float* sW3g,
    int w, int g, int c, float (&partL)[4], float (&partG)[4]) {

    const int l = g * 16 + c;
    partL[0] = partL[1] = partL[2] = partL[3] = 0.f;
    partG[0] = partG[1] = partG[2] = partG[3] = 0.f;

#pragma unroll
    for (int ptb = 0; ptb < 2; ++ptb) {
        // ---- B-fragments for pairs (4w + 2ptb + p, c), p=0,1, both branches
        BF8 bl[2][2], bg[2][2];
#pragma unroll
        for (int kt = 0; kt < 2; ++kt) {
            const float* pjY = &ysj[c][kt * 32 + 8 * g];
            const float4 jy0 = *(const float4*)(pjY);
            const float4 jy1 = *(const float4*)(pjY + 4);
            const float* pjZ = &zsj[c][kt * 32 + 8 * g];
            const float4 jz0 = *(const float4*)(pjZ);
            const float4 jz1 = *(const float4*)(pjZ + 4);
#pragma unroll
            for (int p = 0; p < 2; ++p) {
                const int row = 4 * w + 2 * ptb + p;      // wave-uniform
                const float* piY = &ysi[row][kt * 32 + 8 * g];
                const float4 iy0 = *(const float4*)(piY);
                const float4 iy1 = *(const float4*)(piY + 4);
                bl[kt][p].u[0] = pk2(fast_silu(iy0.x + jy0.x), fast_silu(iy0.y + jy0.y));
                bl[kt][p].u[1] = pk2(fast_silu(iy0.z + jy0.z), fast_silu(iy0.w + jy0.w));
                bl[kt][p].u[2] = pk2(fast_silu(iy1.x + jy1.x), fast_silu(iy1.y + jy1.y));
                bl[kt][p].u[3] = pk2(fast_silu(iy1.z + jy1.z), fast_silu(iy1.w + jy1.w));
                const float* piZ = &zsi[row][kt * 32 + 8 * g];
                const float4 iz0 = *(const float4*)(piZ);
                const float4 iz1 = *(const float4*)(piZ + 4);
                bg[kt][p].u[0] = pk2(fast_silu(iz0.x + jz0.x), fast_silu(iz0.y + jz0.y));
                bg[kt][p].u[1] = pk2(fast_silu(iz0.z + jz0.z), fast_silu(iz0.w + jz0.w));
                bg[kt][p].u[2] = pk2(fast_silu(iz1.x + jz1.x), fast_silu(iz1.y + jz1.y));
                bg[kt][p].u[3] = pk2(fast_silu(iz1.z + jz1.z), fast_silu(iz1.w + jz1.w));
            }
        }

#pragma unroll
        for (int ft = 0; ft < 4; ++ft) {
            const short* baseL = wfL + ft * 512 + l * 8;
            const short* baseG = wfG + ft * 512 + l * 8;
            const bf16x8 wL0 = *(const bf16x8*)(baseL);           // kt=0
            const bf16x8 wL1 = *(const bf16x8*)(baseL + 2048);    // kt=1
            const bf16x8 wG0 = *(const bf16x8*)(baseG);
            const bf16x8 wG1 = *(const bf16x8*)(baseG + 2048);
            const float4 b2l = *(const float4*)&sB2l[ft * 16 + 4 * g];
            const float4 w3l = *(const float4*)&sW3l[ft * 16 + 4 * g];
            const float4 b2g = *(const float4*)&sB2g[ft * 16 + 4 * g];
            const float4 w3g = *(const float4*)&sW3g[ft * 16 + 4 * g];
#pragma unroll
            for (int p = 0; p < 2; ++p) {
                f32x4 accL = (f32x4){b2l.x, b2l.y, b2l.z, b2l.w};
                f32x4 accG = (f32x4){b2g.x, b2g.y, b2g.z, b2g.w};
                accL = __builtin_amdgcn_mfma_f32_16x16x32_bf16(wL0, bl[0][p].v, accL, 0, 0, 0);
                accG = __builtin_amdgcn_mfma_f32_16x16x32_bf16(wG0, bg[0][p].v, accG, 0, 0, 0);
                accL = __builtin_amdgcn_mfma_f32_16x16x32_bf16(wL1, bl[1][p].v, accL, 0, 0, 0);
                accG = __builtin_amdgcn_mfma_f32_16x16x32_bf16(wG1, bg[1][p].v, accG, 0, 0, 0);
                partL[2 * ptb + p] += fast_silu(accL[0]) * w3l.x
                                    + fast_silu(accL[1]) * w3l.y
                                    + fast_silu(accL[2]) * w3l.z
                                    + fast_silu(accL[3]) * w3l.w;
                partG[2 * ptb + p] += fast_silu(accG[0]) * w3g.x
                                    + fast_silu(accG[1]) * w3g.y
                                    + fast_silu(accG[2]) * w3g.z
                                    + fast_silu(accG[3]) * w3g.w;
            }
        }
    }
}

// ---------------------------------------------------------------------------
// Kernel 3: 16x16 pair tile per block (upper triangle), transposed MFMA.
// No waves-per-EU cap: every capped variant (R3/R4/R7) spilled; natural
// live set ~90-110 VGPR is the proven clean regime (R6).
// ---------------------------------------------------------------------------
__global__ __launch_bounds__(256) void pair_mlp_mfma(
    const float* __restrict__ y, const float* __restrict__ z,
    const short* __restrict__ wf,
    const float* __restrict__ lb2, const float* __restrict__ lW3, const float* __restrict__ lb3,
    const float* __restrict__ gb2, const float* __restrict__ gW3, const float* __restrict__ gb3,
    float* __restrict__ out, int N) {

    __shared__ __align__(16) float smem[4608];   // 18432 B
    float (*ysi)[F + 4] = (float (*)[F + 4])(smem + 0);      // 16x68
    float (*zsi)[F + 4] = (float (*)[F + 4])(smem + 1088);
    float (*ysj)[F + 4] = (float (*)[F + 4])(smem + 2176);
    float (*zsj)[F + 4] = (float (*)[F + 4])(smem + 3264);
    float* sB2l = smem + 4352;
    float* sW3l = smem + 4416;
    float* sB2g = smem + 4480;
    float* sW3g = smem + 4544;
    // epilogue aliases (used only after a __syncthreads once y/z reads done)
    float (*valD)[TILE + 1] = (float (*)[TILE + 1])(smem + 0);
    float (*valT)[TILE + 1] = (float (*)[TILE + 1])(smem + 1088);

    const int bid = blockIdx.x;
    int tj = (int)((sqrtf(8.0f * (float)bid + 1.0f) - 1.0f) * 0.5f);
    while ((tj + 1) * (tj + 2) / 2 <= bid) ++tj;
    while (tj * (tj + 1) / 2 > bid) --tj;
    const int ti = bid - tj * (tj + 1) / 2;   // ti <= tj
    const int i0 = ti * TILE, j0 = tj * TILE;

    const int t = threadIdx.x;

    // ---- stage y/z row tiles ----
    {
        const int r = t >> 4;
        const int e4 = t & 15;
        const float4* yv = (const float4*)y;
        const float4* zv = (const float4*)z;
        *(float4*)&ysi[r][e4 * 4] = yv[(size_t)(i0 + r) * (F / 4) + e4];
        *(float4*)&zsi[r][e4 * 4] = zv[(size_t)(i0 + r) * (F / 4) + e4];
        *(float4*)&ysj[r][e4 * 4] = yv[(size_t)(j0 + r) * (F / 4) + e4];
        *(float4*)&zsj[r][e4 * 4] = zv[(size_t)(j0 + r) * (F / 4) + e4];
    }
    if (t < F) {
        sB2l[t] = lb2[t];
        sW3l[t] = lW3[t];
        sB2g[t] = gb2[t];
        sW3g[t] = gW3[t];
    }
    __syncthreads();

    const int w = t >> 6;     // wave 0..3
    const int l = t & 63;
    const int g = l >> 4;
    const int c = l & 15;

    float partL[4], partG[4];
    run_both(ysi, ysj, zsi, zsj, wf, wf + 4096,
             sB2l, sW3l, sB2g, sW3g, w, g, c, partL, partG);

    // ---- reduce across the 4 lane groups (features) ----
#pragma unroll
    for (int pt = 0; pt < 4; ++pt) {
        partL[pt] += __shfl_xor(partL[pt], 16, 64);
        partL[pt] += __shfl_xor(partL[pt], 32, 64);
        partG[pt] += __shfl_xor(partG[pt], 16, 64);
        partG[pt] += __shfl_xor(partG[pt], 32, 64);
    }

    const float b3l = lb3[0];
    const float b3g = gb3[0];

    __syncthreads();   // all y/z LDS reads complete before aliasing region

    if (g == 0) {
#pragma unroll
        for (int pt = 0; pt < 4; ++pt) {
            const float m3 = partL[pt] + b3l;
            const float g3 = partG[pt] + b3g;
            const float v = m3 * fast_sigmoid(g3);
            valD[4 * w + pt][c] = v;
            valT[c][4 * w + pt] = v;
        }
    }
    __syncthreads();

    // ---- single-phase coalesced stores of both mirrored tiles ----
    {
        const int r = t >> 4;
        const int cc = t & 15;
        out[(size_t)(i0 + r) * N + (j0 + cc)] = valD[r][cc];
        out[(size_t)(j0 + r) * N + (i0 + cc)] = valT[r][cc];
    }
}

extern "C" void kernel_launch(void* const* d_in, const int* in_sizes, int n_in,
                              void* d_out, int out_size, void* d_ws, size_t ws_size,
                              hipStream_t stream) {
    const float* node_feat = (const float*)d_in[0];
    const float* lW1 = (const float*)d_in[1];
    const float* lb1 = (const float*)d_in[2];
    const float* lW2 = (const float*)d_in[3];
    const float* lb2 = (const float*)d_in[4];
    const float* lW3 = (const float*)d_in[5];
    const float* lb3 = (const float*)d_in[6];
    const float* gW1 = (const float*)d_in[7];
    const float* gb1 = (const float*)d_in[8];
    const float* gW2 = (const float*)d_in[9];
    const float* gb2 = (const float*)d_in[10];
    const float* gW3 = (const float*)d_in[11];
    const float* gb3 = (const float*)d_in[12];

    const int N = in_sizes[0] / F;   // 1024

    float* y = (float*)d_ws;                     // N*F floats
    float* z = y + (size_t)N * F;                // N*F floats
    short* wfrag = (short*)(z + (size_t)N * F);  // 8192 shorts (16 KB)

    precompute_yz<<<N, F, 0, stream>>>(node_feat, lW1, lb1, gW1, gb1, y, z);
    prep_wfrags<<<32, 256, 0, stream>>>(lW2, gW2, wfrag);

    const int nT = N / TILE;                   // 64
    const int nBlocks = nT * (nT + 1) / 2;     // 2080
    pair_mlp_mfma<<<nBlocks, 256, 0, stream>>>(y, z, wfrag,
                                               lb2, lW3, lb3,
                                               gb2, gW3, gb3,
                                               (float*)d_out, N);
}

// Round 9
// 52.259 us; speedup vs baseline: 1.4086x; 1.1005x over previous
//
#include <hip/hip_runtime.h>
#include <hip/hip_bf16.h>
#include <math.h>

#define F 64
#define TILE 16

typedef __attribute__((ext_vector_type(8))) short bf16x8;
typedef __attribute__((ext_vector_type(4))) float f32x4;

union BF8 { bf16x8 v; unsigned u[4]; };

#define LOG2E 1.4426950408889634f

__device__ __forceinline__ float fast_exp(float x) {          // e^x
    return __builtin_amdgcn_exp2f(x * LOG2E);
}
__device__ __forceinline__ float fast_sigmoid(float x) {
    return __builtin_amdgcn_rcpf(1.0f + fast_exp(-x));
}
__device__ __forceinline__ float fast_silu(float x) {
    return x * __builtin_amdgcn_rcpf(1.0f + fast_exp(-x));
}
// single-instruction pack: low16 = bf16(a), high16 = bf16(b)  (RNE)
__device__ __forceinline__ unsigned cvtpk(float a, float b) {
    unsigned r;
    asm("v_cvt_pk_bf16_f32 %0, %1, %2" : "=v"(r) : "v"(a), "v"(b));
    return r;
}
__device__ __forceinline__ short f2bf(float x) {
    __hip_bfloat16 h = __float2bfloat16(x);
    return __builtin_bit_cast(short, h);
}

// ---------------------------------------------------------------------------
// Kernel 1: per-node half layer-1 outputs (bias folded):
//   y[i][f] = 0.5*(x[i]@lW1)[f] + 0.5*lb1[f];  z likewise for gate branch.
// ---------------------------------------------------------------------------
__global__ void precompute_yz(const float* __restrict__ x,
                              const float* __restrict__ lW1, const float* __restrict__ lb1,
                              const float* __restrict__ gW1, const float* __restrict__ gb1,
                              float* __restrict__ y, float* __restrict__ z) {
    __shared__ float xs[F];
    const int i = blockIdx.x;
    const int f = threadIdx.x;
    xs[f] = x[i * F + f];
    __syncthreads();
    float accY = 0.f, accZ = 0.f;
#pragma unroll
    for (int k = 0; k < F; ++k) {
        const float xv = xs[k];
        accY += xv * lW1[k * F + f];
        accZ += xv * gW1[k * F + f];
    }
    y[i * F + f] = 0.5f * accY + 0.5f * lb1[f];
    z[i * F + f] = 0.5f * accZ + 0.5f * gb1[f];
}

// ---------------------------------------------------------------------------
// Kernel 2: pre-swizzle layer-2 weights into per-lane MFMA fragments
// (A-fragment of W^T == B-fragment of W in the m89 layout), hi bf16 only.
//   wf[ b*4096 + kt*2048 + ft*512 + lane*8 + e ]
//   = bf16(W_b[k][f]),  k = kt*32 + (lane>>4)*8 + e,  f = ft*16 + (lane&15)
// ---------------------------------------------------------------------------
__global__ void prep_wfrags(const float* __restrict__ lW2,
                            const float* __restrict__ gW2,
                            short* __restrict__ wf) {
    const int idx = blockIdx.x * 256 + threadIdx.x;   // 0..8191
    const int e    = idx & 7;
    const int lane = (idx >> 3) & 63;
    const int ft   = (idx >> 9) & 3;
    const int kt   = (idx >> 11) & 1;
    const int b    = (idx >> 12) & 1;
    const int k = kt * 32 + ((lane >> 4) << 3) + e;
    const int f = ft * 16 + (lane & 15);
    const float* W = b ? gW2 : lW2;
    wf[idx] = f2bf(W[k * F + f]);
}

// ---------------------------------------------------------------------------
// One branch: out2^T = W2^T @ act1^T via MFMA, fused layer 3.
// All 4 pair-fragments built once; W-frags and b2/w3 loaded once per ft.
// ---------------------------------------------------------------------------
__device__ __forceinline__ void run_branch(
    const float (*si)[F + 4], const float (*sj)[F + 4],
    const short* __restrict__ wfb,       // branch base (4096 shorts, hi-only)
    const float* sB2, const float* sW3,
    int w, int g, int c, float (&part)[4]) {

    const int l = g * 16 + c;

    // ---- build act1^T B-fragments: lane holds act1[p = l&15][k = kt*32+8g+e]
    BF8 bf[2][4];
#pragma unroll
    for (int kt = 0; kt < 2; ++kt) {
        const float* pj = &sj[c][kt * 32 + 8 * g];
        const float4 j0v = *(const float4*)(pj);
        const float4 j1v = *(const float4*)(pj + 4);
#pragma unroll
        for (int pt = 0; pt < 4; ++pt) {
            const float* pi = &si[4 * w + pt][kt * 32 + 8 * g];  // wave-uniform row
            const float4 i0v = *(const float4*)(pi);
            const float4 i1v = *(const float4*)(pi + 4);
            bf[kt][pt].u[0] = cvtpk(fast_silu(i0v.x + j0v.x), fast_silu(i0v.y + j0v.y));
            bf[kt][pt].u[1] = cvtpk(fast_silu(i0v.z + j0v.z), fast_silu(i0v.w + j0v.w));
            bf[kt][pt].u[2] = cvtpk(fast_silu(i1v.x + j1v.x), fast_silu(i1v.y + j1v.y));
            bf[kt][pt].u[3] = cvtpk(fast_silu(i1v.z + j1v.z), fast_silu(i1v.w + j1v.w));
        }
    }

    part[0] = part[1] = part[2] = part[3] = 0.f;

#pragma unroll
    for (int ft = 0; ft < 4; ++ft) {
        const short* base = wfb + ft * 512 + l * 8;
        const bf16x8 wh0 = *(const bf16x8*)(base);           // kt=0
        const bf16x8 wh1 = *(const bf16x8*)(base + 2048);    // kt=1
        const float4 b2v = *(const float4*)&sB2[ft * 16 + 4 * g];
        const float4 w3v = *(const float4*)&sW3[ft * 16 + 4 * g];
#pragma unroll
        for (int pt = 0; pt < 4; ++pt) {
            f32x4 acc = (f32x4){b2v.x, b2v.y, b2v.z, b2v.w};  // bias preloaded
            acc = __builtin_amdgcn_mfma_f32_16x16x32_bf16(wh0, bf[0][pt].v, acc, 0, 0, 0);
            acc = __builtin_amdgcn_mfma_f32_16x16x32_bf16(wh1, bf[1][pt].v, acc, 0, 0, 0);
            part[pt] += fast_silu(acc[0]) * w3v.x
                      + fast_silu(acc[1]) * w3v.y
                      + fast_silu(acc[2]) * w3v.z
                      + fast_silu(acc[3]) * w3v.w;
        }
    }
}

// ---------------------------------------------------------------------------
// Kernel 3: 16x16 pair tile per block (upper triangle), transposed MFMA.
// No waves-per-EU cap (R3/R4/R7: every cap spilled; natural ~100-116 VGPR
// is the clean regime). Occupancy law: waves/CU ~ 650/VGPR -> ~2 waves/SIMD.
// ---------------------------------------------------------------------------
__global__ __launch_bounds__(256) void pair_mlp_mfma(
    const float* __restrict__ y, const float* __restrict__ z,
    const short* __restrict__ wf,
    const float* __restrict__ lb2, const float* __restrict__ lW3, const float* __restrict__ lb3,
    const float* __restrict__ gb2, const float* __restrict__ gW3, const float* __restrict__ gb3,
    float* __restrict__ out, int N) {

    __shared__ __align__(16) float smem[4608];   // 18432 B
    float (*ysi)[F + 4] = (float (*)[F + 4])(smem + 0);      // 16x68
    float (*zsi)[F + 4] = (float (*)[F + 4])(smem + 1088);
    float (*ysj)[F + 4] = (float (*)[F + 4])(smem + 2176);
    float (*zsj)[F + 4] = (float (*)[F + 4])(smem + 3264);
    float* sB2l = smem + 4352;
    float* sW3l = smem + 4416;
    float* sB2g = smem + 4480;
    float* sW3g = smem + 4544;
    // epilogue aliases (used only after a __syncthreads once y/z reads done)
    float (*valD)[TILE + 1] = (float (*)[TILE + 1])(smem + 0);
    float (*valT)[TILE + 1] = (float (*)[TILE + 1])(smem + 1088);

    const int bid = blockIdx.x;
    int tj = (int)((sqrtf(8.0f * (float)bid + 1.0f) - 1.0f) * 0.5f);
    while ((tj + 1) * (tj + 2) / 2 <= bid) ++tj;
    while (tj * (tj + 1) / 2 > bid) --tj;
    const int ti = bid - tj * (tj + 1) / 2;   // ti <= tj
    const int i0 = ti * TILE, j0 = tj * TILE;

    const int t = threadIdx.x;

    // ---- stage y/z row tiles ----
    {
        const int r = t >> 4;
        const int e4 = t & 15;
        const float4* yv = (const float4*)y;
        const float4* zv = (const float4*)z;
        *(float4*)&ysi[r][e4 * 4] = yv[(size_t)(i0 + r) * (F / 4) + e4];
        *(float4*)&zsi[r][e4 * 4] = zv[(size_t)(i0 + r) * (F / 4) + e4];
        *(float4*)&ysj[r][e4 * 4] = yv[(size_t)(j0 + r) * (F / 4) + e4];
        *(float4*)&zsj[r][e4 * 4] = zv[(size_t)(j0 + r) * (F / 4) + e4];
    }
    if (t < F) {
        sB2l[t] = lb2[t];
        sW3l[t] = lW3[t];
        sB2g[t] = gb2[t];
        sW3g[t] = gW3[t];
    }
    __syncthreads();

    const int w = t >> 6;     // wave 0..3
    const int l = t & 63;
    const int g = l >> 4;
    const int c = l & 15;

    float partL[4], partG[4];
    run_branch(ysi, ysj, wf,        sB2l, sW3l, w, g, c, partL);
    run_branch(zsi, zsj, wf + 4096, sB2g, sW3g, w, g, c, partG);

    // ---- reduce across the 4 lane groups (features) ----
#pragma unroll
    for (int pt = 0; pt < 4; ++pt) {
        partL[pt] += __shfl_xor(partL[pt], 16, 64);
        partL[pt] += __shfl_xor(partL[pt], 32, 64);
        partG[pt] += __shfl_xor(partG[pt], 16, 64);
        partG[pt] += __shfl_xor(partG[pt], 32, 64);
    }

    const float b3l = lb3[0];
    const float b3g = gb3[0];

    __syncthreads();   // all y/z LDS reads complete before aliasing region

    if (g == 0) {
#pragma unroll
        for (int pt = 0; pt < 4; ++pt) {
            const float m3 = partL[pt] + b3l;
            const float g3 = partG[pt] + b3g;
            const float v = m3 * fast_sigmoid(g3);
            valD[4 * w + pt][c] = v;
            valT[c][4 * w + pt] = v;
        }
    }
    __syncthreads();

    // ---- single-phase coalesced stores of both mirrored tiles ----
    {
        const int r = t >> 4;
        const int cc = t & 15;
        out[(size_t)(i0 + r) * N + (j0 + cc)] = valD[r][cc];
        out[(size_t)(j0 + r) * N + (i0 + cc)] = valT[r][cc];
    }
}

extern "C" void kernel_launch(void* const* d_in, const int* in_sizes, int n_in,
                              void* d_out, int out_size, void* d_ws, size_t ws_size,
                              hipStream_t stream) {
    const float* node_feat = (const float*)d_in[0];
    const float* lW1 = (const float*)d_in[1];
    const float* lb1 = (const float*)d_in[2];
    const float* lW2 = (const float*)d_in[3];
    const float* lb2 = (const float*)d_in[4];
    const float* lW3 = (const float*)d_in[5];
    const float* lb3 = (const float*)d_in[6];
    const float* gW1 = (const float*)d_in[7];
    const float* gb1 = (const float*)d_in[8];
    const float* gW2 = (const float*)d_in[9];
    const float* gb2 = (const float*)d_in[10];
    const float* gW3 = (const float*)d_in[11];
    const float* gb3 = (const float*)d_in[12];

    const int N = in_sizes[0] / F;   // 1024

    float* y = (float*)d_ws;                     // N*F floats
    float* z = y + (size_t)N * F;                // N*F floats
    short* wfrag = (short*)(z + (size_t)N * F);  // 8192 shorts (16 KB)

    precompute_yz<<<N, F, 0, stream>>>(node_feat, lW1, lb1, gW1, gb1, y, z);
    prep_wfrags<<<32, 256, 0, stream>>>(lW2, gW2, wfrag);

    const int nT = N / TILE;                   // 64
    const int nBlocks = nT * (nT + 1) / 2;     // 2080
    pair_mlp_mfma<<<nBlocks, 256, 0, stream>>>(y, z, wfrag,
                                               lb2, lW3, lb3,
                                               gb2, gW3, gb3,
                                               (float*)d_out, N);
}